// Round 13
// baseline (183.600 us; speedup 1.0000x reference)
//
#include <hip/hip_runtime.h>

typedef unsigned long long ull;
typedef float f32x4 __attribute__((ext_vector_type(4)));

constexpr int N   = 500;
constexpr int HW  = 60800;    // 200*304
constexpr int NW  = 950;      // HW/64 (exact)
constexpr int NC  = 80;       // num classes
constexpr int NTILES = N * NW / 4;   // 118,750 pack tiles (256 px each)
constexpr int PB  = 1024;     // pack blocks (block 0 does the sort instead)
constexpr int IOUB = 256;     // IoU blocks in node 2 (R9-proven width)
constexpr int QPB = (HW / 4 + 255) / 256;   // 60 blocks of quads per instance

// ~100 us at the fixed 100 MHz s_memrealtime clock. INSTRUMENTATION ONLY:
// appended to every exit path of k_ioudecay to lift it above the harness's
// 68 us fill kernels in the rocprof top-5, exposing its true duration
// (row_dur - pad) and exclusive counters. Remove next round.
constexpr long long PAD_TICKS = 10000;

__device__ __forceinline__ void pad_delay() {
    unsigned long long t0 = __builtin_amdgcn_s_memrealtime();
    while (__builtin_amdgcn_s_memrealtime() - t0 < (unsigned long long)PAD_TICKS) {}
}

// ---------------------------------------------------------------------------
// Node 1. Block 0: stable score sort + per-class CSR + same-class pair list +
// ticket init.  Blocks 1..PB: binarize + bit-pack mask_preds.
__global__ void __launch_bounds__(512)
k_packsort(const float* __restrict__ mp, const int* __restrict__ labels,
           const float* __restrict__ scores,
           ull* __restrict__ packed, int* __restrict__ order_g,
           float* __restrict__ scoresS_g, int* __restrict__ labelsS_g,
           int* __restrict__ offs_g, int* __restrict__ members_g,
           int2* __restrict__ pairList, int* __restrict__ counters) {
    const int t    = threadIdx.x;
    const int lane = t & 63;

    if (blockIdx.x != 0) {
        // ---- pack ----
        int wid = (blockIdx.x - 1) * 8 + (t >> 6);
        for (int tile = wid; tile < NTILES; tile += PB * 8) {
            size_t base = (size_t)tile * 256;
            float v0 = mp[base +   0 + lane];
            float v1 = mp[base +  64 + lane];
            float v2 = mp[base + 128 + lane];
            float v3 = mp[base + 192 + lane];
            ull b0 = __ballot(v0 > 0.5f);
            ull b1 = __ballot(v1 > 0.5f);
            ull b2 = __ballot(v2 > 0.5f);
            ull b3 = __ballot(v3 > 0.5f);
            if (lane == 0) {
                longlong4 w;
                w.x = (long long)b0; w.y = (long long)b1;
                w.z = (long long)b2; w.w = (long long)b3;
                *(longlong4*)(packed + tile * 4) = w;
            }
        }
        return;
    }

    // ---- block 0: init + sort + CSR + pairs ----
    __shared__ float sS[N];
    __shared__ int   orderS[N];
    __shared__ int   labS[N];
    __shared__ int   cnt[NC];
    __shared__ int   offs[NC + 1];
    __shared__ int   members[N];
    __shared__ int   pcnt;

    if (t == 0) { counters[0] = 0; pcnt = 0; }   // done-ticket for node 2
    if (t < N) sS[t] = scores[t];
    if (t < NC) cnt[t] = 0;
    __syncthreads();
    if (t < N) {                       // stable descending rank sort
        float si = sS[t];
        int rank = 0;
        for (int j = 0; j < N; ++j) {
            float sj = sS[j];
            if (sj > si || (sj == si && j < t)) rank++;
        }
        orderS[rank] = t;
    }
    __syncthreads();
    int myLab = -1;
    if (t < N) {
        int o = orderS[t];
        order_g[t]   = o;
        scoresS_g[t] = sS[o];
        myLab = labels[o];
        labS[t] = myLab;
        labelsS_g[t] = myLab;
    }
    __syncthreads();
    if (t < N) atomicAdd(&cnt[myLab], 1);
    __syncthreads();
    if (t == 0) {
        int s = 0;
        for (int c = 0; c < NC; ++c) { offs[c] = s; s += cnt[c]; }
        offs[NC] = s;
    }
    __syncthreads();
    if (t < NC) cnt[t] = offs[t];      // insertion cursors
    __syncthreads();
    if (t < N) { int p = atomicAdd(&cnt[myLab], 1); members[p] = t; }
    __syncthreads();
    if (t < NC) {                      // enumerate same-class pairs (i<j)
        int b = offs[t], e = offs[t + 1];
        for (int a = b; a < e; ++a)
            for (int c2 = a + 1; c2 < e; ++c2) {
                int i = members[a], j = members[c2];
                int lo = min(i, j), hi = max(i, j);
                int p = atomicAdd(&pcnt, 1);
                pairList[p] = make_int2(lo, hi);
            }
    }
    __syncthreads();
    if (t <= NC) offs_g[t] = offs[t];
    if (t < N)   members_g[t] = members[t];
    if (t == 0)  counters[1] = pcnt;   // pairCount
}

// ---------------------------------------------------------------------------
// Node 2. 256 blocks: IoU stripes with LLC write-through atomic stores; after
// a vmcnt drain, a done-ticket elects the last block to run decay+final sort.
// INSTRUMENTED: pad_delay() on every exit path (see PAD_TICKS comment).
__global__ void __launch_bounds__(512)
k_ioudecay(const ull* __restrict__ packed, const int* __restrict__ order_g,
           const float* __restrict__ scoresS_g, const int* __restrict__ labelsS_g,
           const int* __restrict__ offs_g, const int* __restrict__ members_g,
           const int2* __restrict__ pairList, int* __restrict__ counters,
           int* __restrict__ iouI, int* __restrict__ keepOrig_g,
           float* __restrict__ outScores, float* __restrict__ outLabels,
           float* __restrict__ outKeep) {
    const int t    = threadIdx.x;
    const int lane = t & 63;
    __shared__ int sLast;

    // ---- IoU stripes (wave per pair) ----
    int np = counters[1];              // node-1 data (dispatch boundary)
    for (int p = (int)blockIdx.x * 8 + (t >> 6); p < np; p += IOUB * 8) {
        int2 pr = pairList[p];
        const ull* A = packed + (size_t)order_g[pr.x] * NW;
        const ull* B = packed + (size_t)order_g[pr.y] * NW;
        ull acc = 0;  // inter | areaA<<21 | areaB<<42  (fields < 2^17)
        for (int w = lane; w < NW; w += 64) {
            ull a = A[w], b = B[w];
            acc += (ull)__popcll(a & b)
                 + ((ull)__popcll(a) << 21)
                 + ((ull)__popcll(b) << 42);
        }
#pragma unroll
        for (int off = 32; off > 0; off >>= 1) acc += __shfl_down(acc, off, 64);
        if (lane == 0) {
            float inter = (float)(int)(acc & 0x1FFFFF);
            float areaA = (float)(int)((acc >> 21) & 0x1FFFFF);
            float areaB = (float)(int)((acc >> 42) & 0x1FFFFF);
            float uni   = areaA + areaB - inter;    // exact small ints
            __hip_atomic_store(iouI + pr.x * N + pr.y,
                               __float_as_int(inter / uni),
                               __ATOMIC_RELAXED, __HIP_MEMORY_SCOPE_AGENT);
        }
    }
    asm volatile("s_waitcnt vmcnt(0)" ::: "memory");   // stores at LLC
    __syncthreads();                                    // all waves drained
    if (t == 0) sLast = __hip_atomic_fetch_add(counters, 1, __ATOMIC_RELAXED,
                                               __HIP_MEMORY_SCOPE_AGENT);
    __syncthreads();
    if (sLast != IOUB - 1) { pad_delay(); return; }

    // ---- decay + final stable sort (elected block) ----
    __shared__ int   labS[N];
    __shared__ float compS[N];
    __shared__ float sdec[N];
    __shared__ int   offs[NC + 1];
    __shared__ int   members[N];
    if (t < N)  { labS[t] = labelsS_g[t]; members[t] = members_g[t]; }
    if (t <= NC) offs[t] = offs_g[t];
    __syncthreads();
    if (t < N) {                        // comp[j] = max_{i<j same class} iou
        int lj = labS[t];
        float m = 0.f;
        int b = offs[lj], e = offs[lj + 1];
        for (int q = b; q < e; ++q) {
            int i = members[q];
            if (i < t) {
                float v = __int_as_float(__hip_atomic_load(
                    iouI + i * N + t, __ATOMIC_RELAXED, __HIP_MEMORY_SCOPE_AGENT));
                m = fmaxf(m, v);
            }
        }
        compS[t] = m;
    }
    __syncthreads();
    if (t < N) {                        // coefficient (1 bounds the min)
        int lj = labS[t];
        float c = 1.f;
        int b = offs[lj], e = offs[lj + 1];
        for (int q = b; q < e; ++q) {
            int i = members[q];
            if (i < t) {
                float d = __int_as_float(__hip_atomic_load(
                    iouI + i * N + t, __ATOMIC_RELAXED, __HIP_MEMORY_SCOPE_AGENT));
                float ci = compS[i];
                c = fminf(c, expf(-2.f * d * d) / expf(-2.f * ci * ci));  // mirror np
            }
        }
        sdec[t] = scoresS_g[t] * c;
    }
    __syncthreads();
    if (t < N) {                        // stable descending rank on decayed scores
        float sj = sdec[t];
        int rank = 0;
        for (int i = 0; i < N; ++i) {
            float si = sdec[i];
            if (si > sj || (si == sj && i < t)) rank++;
        }
        int o = order_g[t];
        outScores[rank]  = sj;
        outLabels[rank]  = (float)labS[t];
        outKeep[rank]    = (float)o;
        keepOrig_g[rank] = o;
    }
    pad_delay();
}

// ---------------------------------------------------------------------------
// Node 3. Expand kept masks to float output. 2D grid (R9-proven best);
// plain coalesced f32x4 stores.
__global__ void k_gather(const ull* __restrict__ packed, const int* __restrict__ keepOrig,
                         f32x4* __restrict__ outMasks) {
    int q = blockIdx.x * blockDim.x + threadIdx.x;   // quad within instance
    if (q >= HW / 4) return;
    int k    = blockIdx.y;
    int orig = keepOrig[k];                          // uniform -> scalar load
    ull w  = packed[(size_t)orig * NW + (q >> 4)];   // pix = q*4; word = pix>>6
    int sh = (q & 15) * 4;
    f32x4 r;
    r.x = (float)((w >> (sh    )) & 1ULL);
    r.y = (float)((w >> (sh + 1)) & 1ULL);
    r.z = (float)((w >> (sh + 2)) & 1ULL);
    r.w = (float)((w >> (sh + 3)) & 1ULL);
    outMasks[(size_t)k * (HW / 4) + q] = r;
}

// ---------------------------------------------------------------------------
extern "C" void kernel_launch(void* const* d_in, const int* in_sizes, int n_in,
                              void* d_out, int out_size, void* d_ws, size_t ws_size,
                              hipStream_t stream) {
    const float* mask_preds = (const float*)d_in[0];
    const int*   labels     = (const int*)d_in[1];
    const float* scores     = (const float*)d_in[2];

    float*  o         = (float*)d_out;
    float*  outScores = o;
    float*  outLabels = o + N;
    f32x4*  outMasks  = (f32x4*)(o + 2 * N);
    float*  outKeep   = o + 2 * N + (size_t)N * HW;

    // workspace carve-up (16B-aligned chunks; ~5.8 MB total)
    char* w = (char*)d_ws;
    ull*   packed     = (ull*)w;   w += (size_t)N * NW * 8;            // 3,800,000
    int*   order_g    = (int*)w;   w += N * 4;
    float* scoresS_g  = (float*)w; w += N * 4;
    int*   labelsS_g  = (int*)w;   w += N * 4;
    int*   offs_g     = (int*)w;   w += (NC + 4) * 4;
    int*   members_g  = (int*)w;   w += N * 4;
    int*   keepOrig_g = (int*)w;   w += N * 4;
    int*   counters   = (int*)w;   w += 128;   // done-ticket, pairCount
    int*   iouI       = (int*)w;   w += (size_t)N * N * 4;             // 1,000,000
    int2*  pairList   = (int2*)w;  /* N*(N-1)/2 * 8 = 998,000 */

    hipLaunchKernelGGL(k_packsort, dim3(PB + 1), dim3(512), 0, stream,
                       mask_preds, labels, scores, packed, order_g,
                       scoresS_g, labelsS_g, offs_g, members_g, pairList, counters);
    hipLaunchKernelGGL(k_ioudecay, dim3(IOUB), dim3(512), 0, stream,
                       packed, order_g, scoresS_g, labelsS_g, offs_g, members_g,
                       pairList, counters, iouI, keepOrig_g,
                       outScores, outLabels, outKeep);
    hipLaunchKernelGGL(k_gather, dim3(QPB, N), dim3(256), 0, stream,
                       packed, keepOrig_g, outMasks);
}

// Round 14
// 78.234 us; speedup vs baseline: 2.3468x; 2.3468x over previous
//
#include <hip/hip_runtime.h>

typedef unsigned long long ull;
typedef float f32x4 __attribute__((ext_vector_type(4)));

constexpr int N   = 500;
constexpr int HW  = 60800;    // 200*304
constexpr int NW  = 950;      // HW/64 (exact)
constexpr int NC  = 80;       // num classes
constexpr int NTILES = N * NW / 4;   // 118,750 pack tiles (256 px each)
constexpr int PB  = 1024;     // pack blocks (block 0 does the sort instead)
constexpr int IOUB = 256;     // IoU blocks in node 2 (R9-proven width)
constexpr int QPB = (HW / 4 + 255) / 256;   // 60 blocks of quads per instance
constexpr int CHUNK = 3072;   // decay LDS staging chunk (pairs)

// ---------------------------------------------------------------------------
// Node 1. Block 0: stable score sort + per-class CSR + same-class pair list +
// ticket init.  Blocks 1..PB: binarize + bit-pack mask_preds.
__global__ void __launch_bounds__(512)
k_packsort(const float* __restrict__ mp, const int* __restrict__ labels,
           const float* __restrict__ scores,
           ull* __restrict__ packed, int* __restrict__ order_g,
           float* __restrict__ scoresS_g, int* __restrict__ labelsS_g,
           int2* __restrict__ pairList, int* __restrict__ counters) {
    const int t    = threadIdx.x;
    const int lane = t & 63;

    if (blockIdx.x != 0) {
        // ---- pack ----
        int wid = (blockIdx.x - 1) * 8 + (t >> 6);
        for (int tile = wid; tile < NTILES; tile += PB * 8) {
            size_t base = (size_t)tile * 256;
            float v0 = mp[base +   0 + lane];
            float v1 = mp[base +  64 + lane];
            float v2 = mp[base + 128 + lane];
            float v3 = mp[base + 192 + lane];
            ull b0 = __ballot(v0 > 0.5f);
            ull b1 = __ballot(v1 > 0.5f);
            ull b2 = __ballot(v2 > 0.5f);
            ull b3 = __ballot(v3 > 0.5f);
            if (lane == 0) {
                longlong4 w;
                w.x = (long long)b0; w.y = (long long)b1;
                w.z = (long long)b2; w.w = (long long)b3;
                *(longlong4*)(packed + tile * 4) = w;
            }
        }
        return;
    }

    // ---- block 0: init + sort + CSR + pairs ----
    __shared__ float sS[N];
    __shared__ int   orderS[N];
    __shared__ int   labS[N];
    __shared__ int   cnt[NC];
    __shared__ int   offs[NC + 1];
    __shared__ int   members[N];
    __shared__ int   pcnt;

    if (t == 0) { counters[0] = 0; pcnt = 0; }   // done-ticket for node 2
    if (t < N) sS[t] = scores[t];
    if (t < NC) cnt[t] = 0;
    __syncthreads();
    if (t < N) {                       // stable descending rank sort
        float si = sS[t];
        int rank = 0;
        for (int j = 0; j < N; ++j) {
            float sj = sS[j];
            if (sj > si || (sj == si && j < t)) rank++;
        }
        orderS[rank] = t;
    }
    __syncthreads();
    int myLab = -1;
    if (t < N) {
        int o = orderS[t];
        order_g[t]   = o;
        scoresS_g[t] = sS[o];
        myLab = labels[o];
        labS[t] = myLab;
        labelsS_g[t] = myLab;
    }
    __syncthreads();
    if (t < N) atomicAdd(&cnt[myLab], 1);
    __syncthreads();
    if (t == 0) {
        int s = 0;
        for (int c = 0; c < NC; ++c) { offs[c] = s; s += cnt[c]; }
        offs[NC] = s;
    }
    __syncthreads();
    if (t < NC) cnt[t] = offs[t];      // insertion cursors
    __syncthreads();
    if (t < N) { int p = atomicAdd(&cnt[myLab], 1); members[p] = t; }
    __syncthreads();
    if (t < NC) {                      // enumerate same-class pairs (i<j)
        int b = offs[t], e = offs[t + 1];
        for (int a = b; a < e; ++a)
            for (int c2 = a + 1; c2 < e; ++c2) {
                int i = members[a], j = members[c2];
                int lo = min(i, j), hi = max(i, j);
                int p = atomicAdd(&pcnt, 1);
                pairList[p] = make_int2(lo, hi);
            }
    }
    __syncthreads();
    if (t == 0)  counters[1] = pcnt;   // pairCount
}

// ---------------------------------------------------------------------------
// Node 2. 256 blocks: IoU per pair -> compact iouC[p] (LLC write-through);
// vmcnt drain + done-ticket elects the last block, which stages pairs+iou
// into LDS (parallel loads) and reduces comp/coef via LDS atomics.
__global__ void __launch_bounds__(512)
k_ioudecay(const ull* __restrict__ packed, const int* __restrict__ order_g,
           const float* __restrict__ scoresS_g, const int* __restrict__ labelsS_g,
           const int2* __restrict__ pairList, int* __restrict__ counters,
           int* __restrict__ iouC, int* __restrict__ keepOrig_g,
           float* __restrict__ outScores, float* __restrict__ outLabels,
           float* __restrict__ outKeep) {
    const int t    = threadIdx.x;
    const int lane = t & 63;
    __shared__ int sLast;

    // ---- IoU stripes (wave per pair) ----
    int np = counters[1];              // node-1 data (dispatch boundary)
    for (int p = (int)blockIdx.x * 8 + (t >> 6); p < np; p += IOUB * 8) {
        int2 pr = pairList[p];
        const ull* A = packed + (size_t)order_g[pr.x] * NW;
        const ull* B = packed + (size_t)order_g[pr.y] * NW;
        ull acc = 0;  // inter | areaA<<21 | areaB<<42  (fields < 2^17)
        for (int w = lane; w < NW; w += 64) {
            ull a = A[w], b = B[w];
            acc += (ull)__popcll(a & b)
                 + ((ull)__popcll(a) << 21)
                 + ((ull)__popcll(b) << 42);
        }
#pragma unroll
        for (int off = 32; off > 0; off >>= 1) acc += __shfl_down(acc, off, 64);
        if (lane == 0) {
            float inter = (float)(int)(acc & 0x1FFFFF);
            float areaA = (float)(int)((acc >> 21) & 0x1FFFFF);
            float areaB = (float)(int)((acc >> 42) & 0x1FFFFF);
            float uni   = areaA + areaB - inter;    // exact small ints
            __hip_atomic_store(iouC + p, __float_as_int(inter / uni),
                               __ATOMIC_RELAXED, __HIP_MEMORY_SCOPE_AGENT);
        }
    }
    asm volatile("s_waitcnt vmcnt(0)" ::: "memory");   // stores at LLC
    __syncthreads();                                    // all waves drained
    if (t == 0) sLast = __hip_atomic_fetch_add(counters, 1, __ATOMIC_RELAXED,
                                               __HIP_MEMORY_SCOPE_AGENT);
    __syncthreads();
    if (sLast != IOUB - 1) return;

    // ---- decay (elected block): parallel stage + LDS-atomic reduce ----
    __shared__ int   labS[N];
    __shared__ int   compB[N];     // float bits of comp[j]  (init 0.0f)
    __shared__ int   coefB[N];     // float bits of coef[j]  (init 1.0f)
    __shared__ float sdec[N];
    __shared__ int2  pch[CHUNK];
    __shared__ float ich[CHUNK];

    if (t < N) {
        labS[t]  = labelsS_g[t];
        compB[t] = 0;              // 0.0f
        coefB[t] = 0x3F800000;     // 1.0f
    }
    __syncthreads();
    // pass 1: comp[j] = max over pairs (i,j) of iou   (exact, order-free)
    for (int base = 0; base < np; base += CHUNK) {
        int n = min(np - base, CHUNK);
        for (int u = t; u < n; u += 512) {
            pch[u] = pairList[base + u];
            ich[u] = __int_as_float(__hip_atomic_load(
                iouC + base + u, __ATOMIC_RELAXED, __HIP_MEMORY_SCOPE_AGENT));
        }
        __syncthreads();
        for (int u = t; u < n; u += 512)
            atomicMax(&compB[pch[u].y], __float_as_int(ich[u]));
        __syncthreads();
    }
    // pass 2: coef[j] = min over pairs (i,j) of exp(-2d^2)/exp(-2 comp[i]^2)
    for (int base = 0; base < np; base += CHUNK) {
        int n = min(np - base, CHUNK);
        for (int u = t; u < n; u += 512) {
            pch[u] = pairList[base + u];
            ich[u] = __int_as_float(__hip_atomic_load(
                iouC + base + u, __ATOMIC_RELAXED, __HIP_MEMORY_SCOPE_AGENT));
        }
        __syncthreads();
        for (int u = t; u < n; u += 512) {
            float d  = ich[u];
            float ci = __int_as_float(compB[pch[u].x]);
            float r  = expf(-2.f * d * d) / expf(-2.f * ci * ci);  // mirror np
            atomicMin(&coefB[pch[u].y], __float_as_int(r));
        }
        __syncthreads();
    }
    if (t < N) sdec[t] = scoresS_g[t] * __int_as_float(coefB[t]);
    __syncthreads();
    if (t < N) {                        // stable descending rank on decayed scores
        float sj = sdec[t];
        int rank = 0;
        for (int i = 0; i < N; ++i) {
            float si = sdec[i];
            if (si > sj || (si == sj && i < t)) rank++;
        }
        int o = order_g[t];
        outScores[rank]  = sj;
        outLabels[rank]  = (float)labS[t];
        outKeep[rank]    = (float)o;
        keepOrig_g[rank] = o;
    }
}

// ---------------------------------------------------------------------------
// Node 3. Expand kept masks to float output. 2D grid (R9-proven best);
// plain coalesced f32x4 stores.
__global__ void k_gather(const ull* __restrict__ packed, const int* __restrict__ keepOrig,
                         f32x4* __restrict__ outMasks) {
    int q = blockIdx.x * blockDim.x + threadIdx.x;   // quad within instance
    if (q >= HW / 4) return;
    int k    = blockIdx.y;
    int orig = keepOrig[k];                          // uniform -> scalar load
    ull w  = packed[(size_t)orig * NW + (q >> 4)];   // pix = q*4; word = pix>>6
    int sh = (q & 15) * 4;
    f32x4 r;
    r.x = (float)((w >> (sh    )) & 1ULL);
    r.y = (float)((w >> (sh + 1)) & 1ULL);
    r.z = (float)((w >> (sh + 2)) & 1ULL);
    r.w = (float)((w >> (sh + 3)) & 1ULL);
    outMasks[(size_t)k * (HW / 4) + q] = r;
}

// ---------------------------------------------------------------------------
extern "C" void kernel_launch(void* const* d_in, const int* in_sizes, int n_in,
                              void* d_out, int out_size, void* d_ws, size_t ws_size,
                              hipStream_t stream) {
    const float* mask_preds = (const float*)d_in[0];
    const int*   labels     = (const int*)d_in[1];
    const float* scores     = (const float*)d_in[2];

    float*  o         = (float*)d_out;
    float*  outScores = o;
    float*  outLabels = o + N;
    f32x4*  outMasks  = (f32x4*)(o + 2 * N);
    float*  outKeep   = o + 2 * N + (size_t)N * HW;

    // workspace carve-up (16B-aligned chunks; ~5.3 MB total)
    char* w = (char*)d_ws;
    ull*   packed     = (ull*)w;   w += (size_t)N * NW * 8;            // 3,800,000
    int*   order_g    = (int*)w;   w += N * 4;
    float* scoresS_g  = (float*)w; w += N * 4;
    int*   labelsS_g  = (int*)w;   w += N * 4;
    int*   keepOrig_g = (int*)w;   w += N * 4;
    int*   counters   = (int*)w;   w += 128;   // done-ticket, pairCount
    int*   iouC       = (int*)w;   w += (size_t)(N * (N - 1) / 2) * 4; // 499,000
    int2*  pairList   = (int2*)w;  /* N*(N-1)/2 * 8 = 998,000 */

    hipLaunchKernelGGL(k_packsort, dim3(PB + 1), dim3(512), 0, stream,
                       mask_preds, labels, scores, packed, order_g,
                       scoresS_g, labelsS_g, pairList, counters);
    hipLaunchKernelGGL(k_ioudecay, dim3(IOUB), dim3(512), 0, stream,
                       packed, order_g, scoresS_g, labelsS_g,
                       pairList, counters, iouC, keepOrig_g,
                       outScores, outLabels, outKeep);
    hipLaunchKernelGGL(k_gather, dim3(QPB, N), dim3(256), 0, stream,
                       packed, keepOrig_g, outMasks);
}

// Round 15
// 75.678 us; speedup vs baseline: 2.4261x; 1.0338x over previous
//
#include <hip/hip_runtime.h>

typedef unsigned long long ull;
typedef float f32x4 __attribute__((ext_vector_type(4)));

constexpr int N   = 500;
constexpr int HW  = 60800;    // 200*304
constexpr int NW  = 950;      // HW/64 (exact) real words per row
constexpr int NWP = 960;      // padded row stride = 15*64 (uniform unroll)
constexpr int NC  = 80;       // num classes
constexpr int TPR = 475;      // 128-px tiles per row (60800/128, exact)
constexpr int NT2 = N * TPR;  // 237,500 pack tiles
constexpr int PB  = 1024;     // pack blocks (block 0 does the sort instead)
constexpr int IOUB = 256;     // IoU blocks in node 2
constexpr int QPB = (HW / 4 + 255) / 256;   // 60 blocks of quads per instance
constexpr int CHUNK = 3072;   // decay LDS staging chunk (pairs)

// ---------------------------------------------------------------------------
// Node 1. Block 0: stable score sort + per-class CSR + pair list + row-pad
// zero-fill + ticket init.  Blocks 1..PB: binarize + bit-pack mask_preds
// (128-px tiles -> ulonglong2 at padded stride).
__global__ void __launch_bounds__(512)
k_packsort(const float* __restrict__ mp, const int* __restrict__ labels,
           const float* __restrict__ scores,
           ull* __restrict__ packed, int* __restrict__ order_g,
           float* __restrict__ scoresS_g, int* __restrict__ labelsS_g,
           int2* __restrict__ pairList, int* __restrict__ counters) {
    const int t    = threadIdx.x;
    const int lane = t & 63;

    if (blockIdx.x != 0) {
        // ---- pack ----
        int wid = (blockIdx.x - 1) * 8 + (t >> 6);
        for (int tile = wid; tile < NT2; tile += PB * 8) {
            size_t base = (size_t)tile * 128;            // pixel base (exact)
            float v0 = mp[base +  0 + lane];
            float v1 = mp[base + 64 + lane];
            ull b0 = __ballot(v0 > 0.5f);
            ull b1 = __ballot(v1 > 0.5f);
            if (lane == 0) {
                int row = tile / TPR;                    // magic-mul
                int tr  = tile - row * TPR;
                ulonglong2 w2; w2.x = b0; w2.y = b1;
                *(ulonglong2*)(packed + (size_t)row * NWP + tr * 2) = w2;
            }
        }
        return;
    }

    // ---- block 0: pad zero-fill + init + sort + CSR + pairs ----
    __shared__ float sS[N];
    __shared__ int   orderS[N];
    __shared__ int   labS[N];
    __shared__ int   cnt[NC];
    __shared__ int   offs[NC + 1];
    __shared__ int   members[N];
    __shared__ int   pcnt;

    for (int u = t; u < N * (NWP - NW); u += 512) {      // zero rows' pad words
        int row = u / (NWP - NW), w = u - row * (NWP - NW);
        packed[(size_t)row * NWP + NW + w] = 0ULL;
    }
    if (t == 0) { counters[0] = 0; pcnt = 0; }   // done-ticket for node 2
    if (t < N) sS[t] = scores[t];
    if (t < NC) cnt[t] = 0;
    __syncthreads();
    if (t < N) {                       // stable descending rank sort
        float si = sS[t];
        int rank = 0;
        for (int j = 0; j < N; ++j) {
            float sj = sS[j];
            if (sj > si || (sj == si && j < t)) rank++;
        }
        orderS[rank] = t;
    }
    __syncthreads();
    int myLab = -1;
    if (t < N) {
        int o = orderS[t];
        order_g[t]   = o;
        scoresS_g[t] = sS[o];
        myLab = labels[o];
        labS[t] = myLab;
        labelsS_g[t] = myLab;
    }
    __syncthreads();
    if (t < N) atomicAdd(&cnt[myLab], 1);
    __syncthreads();
    if (t == 0) {
        int s = 0;
        for (int c = 0; c < NC; ++c) { offs[c] = s; s += cnt[c]; }
        offs[NC] = s;
    }
    __syncthreads();
    if (t < NC) cnt[t] = offs[t];      // insertion cursors
    __syncthreads();
    if (t < N) { int p = atomicAdd(&cnt[myLab], 1); members[p] = t; }
    __syncthreads();
    if (t < NC) {                      // enumerate same-class pairs (i<j)
        int b = offs[t], e = offs[t + 1];
        for (int a = b; a < e; ++a)
            for (int c2 = a + 1; c2 < e; ++c2) {
                int i = members[a], j = members[c2];
                int lo = min(i, j), hi = max(i, j);
                int p = atomicAdd(&pcnt, 1);
                pairList[p] = make_int2(lo, hi);
            }
    }
    __syncthreads();
    if (t == 0)  counters[1] = pcnt;   // pairCount
}

// ---------------------------------------------------------------------------
// Node 2. 256 blocks: IoU per pair with a FULLY-UNROLLED 15-iteration word
// loop (uniform thanks to the 960-word padded stride) -> all 30 loads in
// flight at once, one latency exposure. Then vmcnt drain + done-ticket
// elects the last block for the LDS-reduce decay + final sort (R14-proven).
__global__ void __launch_bounds__(512)
k_ioudecay(const ull* __restrict__ packed, const int* __restrict__ order_g,
           const float* __restrict__ scoresS_g, const int* __restrict__ labelsS_g,
           const int2* __restrict__ pairList, int* __restrict__ counters,
           int* __restrict__ iouC, int* __restrict__ keepOrig_g,
           float* __restrict__ outScores, float* __restrict__ outLabels,
           float* __restrict__ outKeep) {
    const int t    = threadIdx.x;
    const int lane = t & 63;
    __shared__ int sLast;

    // ---- IoU stripes (wave per pair) ----
    int np = counters[1];              // node-1 data (dispatch boundary)
    for (int p = (int)blockIdx.x * 8 + (t >> 6); p < np; p += IOUB * 8) {
        int2 pr = pairList[p];
        const ull* A = packed + (size_t)order_g[pr.x] * NWP + lane;
        const ull* B = packed + (size_t)order_g[pr.y] * NWP + lane;
        ull acc = 0;  // inter | areaA<<21 | areaB<<42  (fields < 2^17)
#pragma unroll
        for (int k = 0; k < 15; ++k) {                   // uniform, unrolled
            ull a = A[k * 64], b = B[k * 64];
            acc += (ull)__popcll(a & b)
                 + ((ull)__popcll(a) << 21)
                 + ((ull)__popcll(b) << 42);
        }
#pragma unroll
        for (int off = 32; off > 0; off >>= 1) acc += __shfl_down(acc, off, 64);
        if (lane == 0) {
            float inter = (float)(int)(acc & 0x1FFFFF);
            float areaA = (float)(int)((acc >> 21) & 0x1FFFFF);
            float areaB = (float)(int)((acc >> 42) & 0x1FFFFF);
            float uni   = areaA + areaB - inter;    // exact small ints
            __hip_atomic_store(iouC + p, __float_as_int(inter / uni),
                               __ATOMIC_RELAXED, __HIP_MEMORY_SCOPE_AGENT);
        }
    }
    asm volatile("s_waitcnt vmcnt(0)" ::: "memory");   // stores at LLC
    __syncthreads();                                    // all waves drained
    if (t == 0) sLast = __hip_atomic_fetch_add(counters, 1, __ATOMIC_RELAXED,
                                               __HIP_MEMORY_SCOPE_AGENT);
    __syncthreads();
    if (sLast != IOUB - 1) return;

    // ---- decay (elected block): parallel stage + LDS-atomic reduce ----
    __shared__ int   labS[N];
    __shared__ int   compB[N];     // float bits of comp[j]  (init 0.0f)
    __shared__ int   coefB[N];     // float bits of coef[j]  (init 1.0f)
    __shared__ float sdec[N];
    __shared__ int2  pch[CHUNK];
    __shared__ float ich[CHUNK];

    if (t < N) {
        labS[t]  = labelsS_g[t];
        compB[t] = 0;              // 0.0f
        coefB[t] = 0x3F800000;     // 1.0f
    }
    __syncthreads();
    // pass 1: comp[j] = max over pairs (i,j) of iou   (exact, order-free)
    for (int base = 0; base < np; base += CHUNK) {
        int n = min(np - base, CHUNK);
        for (int u = t; u < n; u += 512) {
            pch[u] = pairList[base + u];
            ich[u] = __int_as_float(__hip_atomic_load(
                iouC + base + u, __ATOMIC_RELAXED, __HIP_MEMORY_SCOPE_AGENT));
        }
        __syncthreads();
        for (int u = t; u < n; u += 512)
            atomicMax(&compB[pch[u].y], __float_as_int(ich[u]));
        __syncthreads();
    }
    // pass 2: coef[j] = min over pairs (i,j) of exp(-2d^2)/exp(-2 comp[i]^2)
    for (int base = 0; base < np; base += CHUNK) {
        int n = min(np - base, CHUNK);
        for (int u = t; u < n; u += 512) {
            pch[u] = pairList[base + u];
            ich[u] = __int_as_float(__hip_atomic_load(
                iouC + base + u, __ATOMIC_RELAXED, __HIP_MEMORY_SCOPE_AGENT));
        }
        __syncthreads();
        for (int u = t; u < n; u += 512) {
            float d  = ich[u];
            float ci = __int_as_float(compB[pch[u].x]);
            float r  = expf(-2.f * d * d) / expf(-2.f * ci * ci);  // mirror np
            atomicMin(&coefB[pch[u].y], __float_as_int(r));
        }
        __syncthreads();
    }
    if (t < N) sdec[t] = scoresS_g[t] * __int_as_float(coefB[t]);
    __syncthreads();
    if (t < N) {                        // stable descending rank on decayed scores
        float sj = sdec[t];
        int rank = 0;
        for (int i = 0; i < N; ++i) {
            float si = sdec[i];
            if (si > sj || (si == sj && i < t)) rank++;
        }
        int o = order_g[t];
        outScores[rank]  = sj;
        outLabels[rank]  = (float)labS[t];
        outKeep[rank]    = (float)o;
        keepOrig_g[rank] = o;
    }
}

// ---------------------------------------------------------------------------
// Node 3. Expand kept masks to float output. 2D grid (R9-proven best);
// plain coalesced f32x4 stores; padded row stride.
__global__ void k_gather(const ull* __restrict__ packed, const int* __restrict__ keepOrig,
                         f32x4* __restrict__ outMasks) {
    int q = blockIdx.x * blockDim.x + threadIdx.x;   // quad within instance
    if (q >= HW / 4) return;
    int k    = blockIdx.y;
    int orig = keepOrig[k];                          // uniform -> scalar load
    ull w  = packed[(size_t)orig * NWP + (q >> 4)];  // pix = q*4; word = pix>>6
    int sh = (q & 15) * 4;
    f32x4 r;
    r.x = (float)((w >> (sh    )) & 1ULL);
    r.y = (float)((w >> (sh + 1)) & 1ULL);
    r.z = (float)((w >> (sh + 2)) & 1ULL);
    r.w = (float)((w >> (sh + 3)) & 1ULL);
    outMasks[(size_t)k * (HW / 4) + q] = r;
}

// ---------------------------------------------------------------------------
extern "C" void kernel_launch(void* const* d_in, const int* in_sizes, int n_in,
                              void* d_out, int out_size, void* d_ws, size_t ws_size,
                              hipStream_t stream) {
    const float* mask_preds = (const float*)d_in[0];
    const int*   labels     = (const int*)d_in[1];
    const float* scores     = (const float*)d_in[2];

    float*  o         = (float*)d_out;
    float*  outScores = o;
    float*  outLabels = o + N;
    f32x4*  outMasks  = (f32x4*)(o + 2 * N);
    float*  outKeep   = o + 2 * N + (size_t)N * HW;

    // workspace carve-up (16B-aligned chunks; ~5.4 MB total)
    char* w = (char*)d_ws;
    ull*   packed     = (ull*)w;   w += (size_t)N * NWP * 8;           // 3,840,000
    int*   order_g    = (int*)w;   w += N * 4;
    float* scoresS_g  = (float*)w; w += N * 4;
    int*   labelsS_g  = (int*)w;   w += N * 4;
    int*   keepOrig_g = (int*)w;   w += N * 4;
    int*   counters   = (int*)w;   w += 128;   // done-ticket, pairCount
    int*   iouC       = (int*)w;   w += (size_t)(N * (N - 1) / 2) * 4; // 499,000
    int2*  pairList   = (int2*)w;  /* N*(N-1)/2 * 8 = 998,000 */

    hipLaunchKernelGGL(k_packsort, dim3(PB + 1), dim3(512), 0, stream,
                       mask_preds, labels, scores, packed, order_g,
                       scoresS_g, labelsS_g, pairList, counters);
    hipLaunchKernelGGL(k_ioudecay, dim3(IOUB), dim3(512), 0, stream,
                       packed, order_g, scoresS_g, labelsS_g,
                       pairList, counters, iouC, keepOrig_g,
                       outScores, outLabels, outKeep);
    hipLaunchKernelGGL(k_gather, dim3(QPB, N), dim3(256), 0, stream,
                       packed, keepOrig_g, outMasks);
}